// Round 3
// baseline (386.922 us; speedup 1.0000x reference)
//
#include <hip/hip_runtime.h>

#define SDIM 2048
#define NHEADS 16
#define HD 64

typedef __attribute__((ext_vector_type(8))) short bf16x8;
typedef __attribute__((ext_vector_type(8))) unsigned short u16x8;
typedef __attribute__((ext_vector_type(4))) float f32x4;
typedef unsigned short u16;

static __device__ __forceinline__ u16 f2bf(float f) {
  unsigned u = __builtin_bit_cast(unsigned, f);
  u += 0x7fffu + ((u >> 16) & 1u);   // RNE
  return (u16)(u >> 16);
}

static __device__ __forceinline__ f32x4 mfma16(bf16x8 a, bf16x8 b, f32x4 c) {
  return __builtin_amdgcn_mfma_f32_16x16x32_bf16(a, b, c, 0, 0, 0);
}

// ---------- prep: fp32 -> bf16, 8 elems/thread ----------
__global__ void cvt_kernel(const float* __restrict__ in, u16* __restrict__ out, int n8) {
  int i = blockIdx.x * blockDim.x + threadIdx.x;
  if (i >= n8) return;
  const float4* p = (const float4*)(in + (long)i * 8);
  float4 a = p[0], b = p[1];
  u16x8 r;
  r[0] = f2bf(a.x); r[1] = f2bf(a.y); r[2] = f2bf(a.z); r[3] = f2bf(a.w);
  r[4] = f2bf(b.x); r[5] = f2bf(b.y); r[6] = f2bf(b.z); r[7] = f2bf(b.w);
  *(u16x8*)(out + (long)i * 8) = r;
}

// ---------- prep: W [K][N] fp32 -> Wt [N][K] bf16 ----------
__global__ void transpose_cvt(const float* __restrict__ W, u16* __restrict__ Wt, int K, int N) {
  __shared__ float t[32][33];
  int tx = threadIdx.x & 31, ty = threadIdx.x >> 5;   // 32 x 8
  int n0 = blockIdx.x * 32, k0 = blockIdx.y * 32;
#pragma unroll
  for (int i = 0; i < 32; i += 8) t[ty + i][tx] = W[(long)(k0 + ty + i) * N + n0 + tx];
  __syncthreads();
#pragma unroll
  for (int i = 0; i < 32; i += 8) Wt[(long)(n0 + ty + i) * K + k0 + tx] = f2bf(t[tx][ty + i]);
}

// ---------- V part of QKV [4096][3072] -> Vt [32][64][2048] bf16 ----------
__global__ __launch_bounds__(256) void vtrans_kernel(const u16* __restrict__ QKV,
                                                     u16* __restrict__ Vt) {
  __shared__ u16 t[64][72];
  const int bh = blockIdx.y, s0 = blockIdx.x * 64;
  const int b = bh >> 4, h = bh & 15;
  const u16* src = QKV + ((long)(b * SDIM + s0)) * 3072 + h * 192 + 128;
  int r = threadIdx.x >> 3, c = (threadIdx.x & 7) * 8;
  *(uint4*)&t[r][c]      = *(const uint4*)(src + (long)r * 3072 + c);
  *(uint4*)&t[r + 32][c] = *(const uint4*)(src + (long)(r + 32) * 3072 + c);
  __syncthreads();
  int d = threadIdx.x >> 2, sc = (threadIdx.x & 3) * 16;
  u16 tmp[16];
#pragma unroll
  for (int k = 0; k < 16; ++k) tmp[k] = t[sc + k][d];
  u16* dst = Vt + ((long)(bh * HD + d)) * SDIM + s0 + sc;
  *(uint4*)dst = *(uint4*)&tmp[0];
  *(uint4*)(dst + 8) = *(uint4*)&tmp[8];
}

// ---------- bf16 GEMM, 128x128x64 tile, 4 waves ----------
// A [M][K] bf16 row-major, Bt [N][K] bf16, C = A*B + bias
// EPI==0: fp32 out Cf.  EPI==1: bf16 out Cb. Both plain [M][N] coalesced.
template <int EPI>
__global__ __launch_bounds__(256) void gemm_bf16(
    const u16* __restrict__ A, const u16* __restrict__ Bt,
    const float* __restrict__ bias, float* __restrict__ Cf, u16* __restrict__ Cb,
    int M, int N, int K)
{
  __shared__ __align__(16) u16 As[128][72];
  __shared__ __align__(16) u16 Bs[128][72];
  const int tid = threadIdx.x, lane = tid & 63, wid = tid >> 6;
  const int wm = wid >> 1, wn = wid & 1;
  const int l15 = lane & 15, l4 = lane >> 4;
  const int m0 = blockIdx.y * 128, n0 = blockIdx.x * 128;
  const int ro = (tid & 7) * 8;

  f32x4 acc[4][4];
#pragma unroll
  for (int i = 0; i < 4; ++i)
#pragma unroll
    for (int j = 0; j < 4; ++j) acc[i][j] = {0.f, 0.f, 0.f, 0.f};

  uint4 ar[4], br[4];
  auto issue = [&](int kc) {
#pragma unroll
    for (int i = 0; i < 4; ++i) {
      int r = (tid >> 3) + i * 32;
      ar[i] = *(const uint4*)(A  + (long)(m0 + r) * K + kc + ro);
      br[i] = *(const uint4*)(Bt + (long)(n0 + r) * K + kc + ro);
    }
  };
  auto commit = [&]() {
#pragma unroll
    for (int i = 0; i < 4; ++i) {
      int r = (tid >> 3) + i * 32;
      *(uint4*)&As[r][ro] = ar[i];
      *(uint4*)&Bs[r][ro] = br[i];
    }
  };

  issue(0);
  const int nk = K >> 6;
  for (int kt = 0; kt < nk; ++kt) {
    commit();
    __syncthreads();
    if (kt + 1 < nk) issue((kt + 1) << 6);
#pragma unroll
    for (int kk = 0; kk < 2; ++kk) {
      bf16x8 af[4], bfr[4];
#pragma unroll
      for (int mt = 0; mt < 4; ++mt)
        af[mt] = *(const bf16x8*)&As[wm * 64 + mt * 16 + l15][kk * 32 + l4 * 8];
#pragma unroll
      for (int nt = 0; nt < 4; ++nt)
        bfr[nt] = *(const bf16x8*)&Bs[wn * 64 + nt * 16 + l15][kk * 32 + l4 * 8];
#pragma unroll
      for (int mt = 0; mt < 4; ++mt)
#pragma unroll
        for (int nt = 0; nt < 4; ++nt)
          acc[mt][nt] = mfma16(af[mt], bfr[nt], acc[mt][nt]);
    }
    __syncthreads();
  }

#pragma unroll
  for (int mt = 0; mt < 4; ++mt)
#pragma unroll
    for (int nt = 0; nt < 4; ++nt)
#pragma unroll
      for (int r = 0; r < 4; ++r) {
        int row = m0 + wm * 64 + mt * 16 + l4 * 4 + r;
        int col = n0 + wn * 64 + nt * 16 + l15;
        float v = acc[mt][nt][r] + bias[col];
        if (EPI == 0) Cf[(long)row * N + col] = v;
        else          Cb[(long)row * N + col] = f2bf(v);
      }
}

// ---------- flash attention: grid (S/64, B*H), 4 waves x 16 q-rows, KBLK=64 ----------
// Q,K read from QKV [4096][3072]; V read directly from global Vt (L2-resident).
__global__ __launch_bounds__(256, 3) void attn_kernel(
    const u16* __restrict__ QKV, const u16* __restrict__ Vtg,
    const int* __restrict__ maskg, u16* __restrict__ Og)
{
  __shared__ __align__(16) u16 Ks[2][64][72];
  __shared__ __align__(16) u16 Ps[64][72];
  const int tid = threadIdx.x, lane = tid & 63, w = tid >> 6;
  const int l15 = lane & 15, l4 = lane >> 4;
  const int bh = blockIdx.y, qt = blockIdx.x;
  const int b = bh >> 4, h = bh & 15;
  const u16* Qp = QKV + ((long)(b * SDIM + qt * 64)) * 3072 + h * 192;
  const u16* Kp = QKV + (long)(b * SDIM) * 3072 + h * 192 + 64;
  const u16* Vp = Vtg + (long)bh * HD * SDIM;
  const int* mp = maskg + b * SDIM;
  const int so = (tid & 7) * 8;
  const float SC = 0.18033688011112042f;   // log2(e) / sqrt(64)

  bf16x8 qa[2];
#pragma unroll
  for (int ks = 0; ks < 2; ++ks)
    qa[ks] = *(const bf16x8*)(Qp + (long)(w * 16 + l15) * 3072 + ks * 32 + l4 * 8);

  f32x4 O[4];
  float mrow[4], lrow[4];
#pragma unroll
  for (int dt = 0; dt < 4; ++dt) O[dt] = {0.f, 0.f, 0.f, 0.f};
#pragma unroll
  for (int r = 0; r < 4; ++r) { mrow[r] = -1e30f; lrow[r] = 0.f; }

  uint4 kr[2];
  auto issue = [&](int kt2) {
#pragma unroll
    for (int i = 0; i < 2; ++i) {
      int r = (tid >> 3) + i * 32;
      kr[i] = *(const uint4*)(Kp + (long)(kt2 * 64 + r) * 3072 + so);
    }
  };
  auto commit = [&](int buf) {
#pragma unroll
    for (int i = 0; i < 2; ++i) {
      int r = (tid >> 3) + i * 32;
      *(uint4*)&Ks[buf][r][so] = kr[i];
    }
  };

  issue(0); commit(0);
  __syncthreads();

  for (int kt = 0; kt < SDIM / 64; ++kt) {
    const int cur = kt & 1;
    if (kt + 1 < SDIM / 64) issue(kt + 1);

    // prefetch V fragments for this tile from global (L2-resident, reused by all q-blocks)
    bf16x8 vb[2][4];
#pragma unroll
    for (int ks2 = 0; ks2 < 2; ++ks2)
#pragma unroll
      for (int dt = 0; dt < 4; ++dt)
        vb[ks2][dt] = *(const bf16x8*)(Vp + (long)(dt * 16 + l15) * SDIM + kt * 64 + ks2 * 32 + l4 * 8);

    float mb[4];
#pragma unroll
    for (int nt = 0; nt < 4; ++nt)
      mb[nt] = mp[kt * 64 + nt * 16 + l15] ? 0.f : -1e30f;

    // S = Q K^T (per wave: 16 x 64), already in log2 domain after *SC
    f32x4 sc4[4];
#pragma unroll
    for (int nt = 0; nt < 4; ++nt) {
      bf16x8 kb0 = *(const bf16x8*)&Ks[cur][nt * 16 + l15][l4 * 8];
      bf16x8 kb1 = *(const bf16x8*)&Ks[cur][nt * 16 + l15][32 + l4 * 8];
      f32x4 z = {0.f, 0.f, 0.f, 0.f};
      z = mfma16(qa[0], kb0, z);
      z = mfma16(qa[1], kb1, z);
      sc4[nt] = z;
    }

    // online softmax (exp2 domain) + P -> LDS (bf16)
#pragma unroll
    for (int r = 0; r < 4; ++r) {
      float s0 = sc4[0][r] * SC + mb[0];
      float s1 = sc4[1][r] * SC + mb[1];
      float s2 = sc4[2][r] * SC + mb[2];
      float s3 = sc4[3][r] * SC + mb[3];
      float mx = fmaxf(fmaxf(s0, s1), fmaxf(s2, s3));
#pragma unroll
      for (int off = 1; off < 16; off <<= 1) mx = fmaxf(mx, __shfl_xor(mx, off));
      float mold = mrow[r];
      float mn = fmaxf(mold, mx);
      mrow[r] = mn;
      float p0 = __builtin_amdgcn_exp2f(s0 - mn), p1 = __builtin_amdgcn_exp2f(s1 - mn);
      float p2 = __builtin_amdgcn_exp2f(s2 - mn), p3 = __builtin_amdgcn_exp2f(s3 - mn);
      float rs = p0 + p1 + p2 + p3;
#pragma unroll
      for (int off = 1; off < 16; off <<= 1) rs += __shfl_xor(rs, off);
      if (mx > mold) {              // rescale only when the running max grew
        float al = __builtin_amdgcn_exp2f(mold - mn);
        lrow[r] = lrow[r] * al + rs;
#pragma unroll
        for (int dt = 0; dt < 4; ++dt) O[dt][r] *= al;   // FIX: per-row rescale, not whole vector
      } else {
        lrow[r] += rs;
      }
      int prow = w * 16 + l4 * 4 + r;
      Ps[prow][0 + l15]  = f2bf(p0);
      Ps[prow][16 + l15] = f2bf(p1);
      Ps[prow][32 + l15] = f2bf(p2);
      Ps[prow][48 + l15] = f2bf(p3);
    }
    // P consumed by the same wave only -> lgkmcnt drain, no barrier
    asm volatile("s_waitcnt lgkmcnt(0)" ::: "memory");
    __builtin_amdgcn_sched_barrier(0);

    // O += P V
#pragma unroll
    for (int ks2 = 0; ks2 < 2; ++ks2) {
      bf16x8 pa = *(const bf16x8*)&Ps[w * 16 + l15][ks2 * 32 + l4 * 8];
#pragma unroll
      for (int dt = 0; dt < 4; ++dt)
        O[dt] = mfma16(pa, vb[ks2][dt], O[dt]);
    }
    if (kt + 1 < SDIM / 64) commit(cur ^ 1);
    __syncthreads();   // only barrier per k-tile (double-buffered K)
  }

#pragma unroll
  for (int dt = 0; dt < 4; ++dt)
#pragma unroll
    for (int r = 0; r < 4; ++r) {
      int s = qt * 64 + w * 16 + l4 * 4 + r;
      int d = dt * 16 + l15;
      float o = O[dt][r] / lrow[r];
      Og[((long)(b * SDIM + s)) * 1024 + h * HD + d] = f2bf(o);
    }
}

extern "C" void kernel_launch(void* const* d_in, const int* in_sizes, int n_in,
                              void* d_out, int out_size, void* d_ws, size_t ws_size,
                              hipStream_t stream) {
  const float* x    = (const float*)d_in[0];
  const int*   am   = (const int*)d_in[1];
  const float* Wqkv = (const float*)d_in[2];
  const float* bqkv = (const float*)d_in[3];
  const float* Wout = (const float*)d_in[4];
  const float* bout = (const float*)d_in[5];
  float* out = (float*)d_out;
  char* ws = (char*)d_ws;

  u16* xb   = (u16*)(ws);                             // 8 MB   x bf16 [4096][1024]
  u16* AOb  = (u16*)(ws);                             // reused after QKV gemm: attn out bf16
  u16* wqt  = (u16*)(ws + (size_t) 8 * 1024 * 1024);  // 6 MB   W_qkv^T bf16 [3072][1024]
  u16* wot  = (u16*)(ws + (size_t)14 * 1024 * 1024);  // 2 MB   W_out^T bf16 [1024][1024]
  u16* QKVb = (u16*)(ws + (size_t)16 * 1024 * 1024);  // 24 MB  qkv bf16 [4096][3072]
  u16* Vtb  = (u16*)(ws + (size_t)40 * 1024 * 1024);  // 8 MB   V^T bf16 [32][64][2048]

  cvt_kernel<<<2048, 256, 0, stream>>>(x, xb, 524288);
  transpose_cvt<<<dim3(96, 32), 256, 0, stream>>>(Wqkv, wqt, 1024, 3072);
  transpose_cvt<<<dim3(32, 32), 256, 0, stream>>>(Wout, wot, 1024, 1024);
  gemm_bf16<1><<<dim3(24, 32), 256, 0, stream>>>(xb, wqt, bqkv, nullptr, QKVb,
                                                 4096, 3072, 1024);
  vtrans_kernel<<<dim3(32, 32), 256, 0, stream>>>(QKVb, Vtb);
  attn_kernel<<<dim3(32, 32), 256, 0, stream>>>(QKVb, Vtb, am, AOb);
  gemm_bf16<0><<<dim3(8, 32), 256, 0, stream>>>(AOb, wot, bout, out, nullptr,
                                                4096, 1024, 1024);
}

// Round 4
// 291.349 us; speedup vs baseline: 1.3280x; 1.3280x over previous
//
#include <hip/hip_runtime.h>

#define SDIM 2048
#define NHEADS 16
#define HD 64

typedef __attribute__((ext_vector_type(8))) short bf16x8;
typedef __attribute__((ext_vector_type(8))) unsigned short u16x8;
typedef __attribute__((ext_vector_type(4))) float f32x4;
typedef unsigned short u16;

static __device__ __forceinline__ u16 f2bf(float f) {
  unsigned u = __builtin_bit_cast(unsigned, f);
  u += 0x7fffu + ((u >> 16) & 1u);   // RNE
  return (u16)(u >> 16);
}

static __device__ __forceinline__ f32x4 mfma16(bf16x8 a, bf16x8 b, f32x4 c) {
  return __builtin_amdgcn_mfma_f32_16x16x32_bf16(a, b, c, 0, 0, 0);
}

// ---------- prep: fp32 -> bf16, 8 elems/thread ----------
__global__ void cvt_kernel(const float* __restrict__ in, u16* __restrict__ out, int n8) {
  int i = blockIdx.x * blockDim.x + threadIdx.x;
  if (i >= n8) return;
  const float4* p = (const float4*)(in + (long)i * 8);
  float4 a = p[0], b = p[1];
  u16x8 r;
  r[0] = f2bf(a.x); r[1] = f2bf(a.y); r[2] = f2bf(a.z); r[3] = f2bf(a.w);
  r[4] = f2bf(b.x); r[5] = f2bf(b.y); r[6] = f2bf(b.z); r[7] = f2bf(b.w);
  *(u16x8*)(out + (long)i * 8) = r;
}

// ---------- prep: W [K][N] fp32 -> Wt [N][K] bf16 ----------
__global__ void transpose_cvt(const float* __restrict__ W, u16* __restrict__ Wt, int K, int N) {
  __shared__ float t[32][33];
  int tx = threadIdx.x & 31, ty = threadIdx.x >> 5;   // 32 x 8
  int n0 = blockIdx.x * 32, k0 = blockIdx.y * 32;
#pragma unroll
  for (int i = 0; i < 32; i += 8) t[ty + i][tx] = W[(long)(k0 + ty + i) * N + n0 + tx];
  __syncthreads();
#pragma unroll
  for (int i = 0; i < 32; i += 8) Wt[(long)(n0 + ty + i) * K + k0 + tx] = f2bf(t[tx][ty + i]);
}

// ---------- V part of QKV [4096][3072] -> Vt [32][64][2048] bf16 ----------
__global__ __launch_bounds__(256) void vtrans_kernel(const u16* __restrict__ QKV,
                                                     u16* __restrict__ Vt) {
  __shared__ u16 t[64][72];
  const int bh = blockIdx.y, s0 = blockIdx.x * 64;
  const int b = bh >> 4, h = bh & 15;
  const u16* src = QKV + ((long)(b * SDIM + s0)) * 3072 + h * 192 + 128;
  int r = threadIdx.x >> 3, c = (threadIdx.x & 7) * 8;
  *(uint4*)&t[r][c]      = *(const uint4*)(src + (long)r * 3072 + c);
  *(uint4*)&t[r + 32][c] = *(const uint4*)(src + (long)(r + 32) * 3072 + c);
  __syncthreads();
  int d = threadIdx.x >> 2, sc = (threadIdx.x & 3) * 16;
  u16 tmp[16];
#pragma unroll
  for (int k = 0; k < 16; ++k) tmp[k] = t[sc + k][d];
  u16* dst = Vt + ((long)(bh * HD + d)) * SDIM + s0 + sc;
  *(uint4*)dst = *(uint4*)&tmp[0];
  *(uint4*)(dst + 8) = *(uint4*)&tmp[8];
}

// ---------- bf16 GEMM, 128x128x64 tile, 4 waves ----------
template <int EPI>
__global__ __launch_bounds__(256) void gemm_bf16(
    const u16* __restrict__ A, const u16* __restrict__ Bt,
    const float* __restrict__ bias, float* __restrict__ Cf, u16* __restrict__ Cb,
    int M, int N, int K)
{
  __shared__ __align__(16) u16 As[128][72];
  __shared__ __align__(16) u16 Bs[128][72];
  const int tid = threadIdx.x, lane = tid & 63, wid = tid >> 6;
  const int wm = wid >> 1, wn = wid & 1;
  const int l15 = lane & 15, l4 = lane >> 4;
  const int m0 = blockIdx.y * 128, n0 = blockIdx.x * 128;
  const int ro = (tid & 7) * 8;

  f32x4 acc[4][4];
#pragma unroll
  for (int i = 0; i < 4; ++i)
#pragma unroll
    for (int j = 0; j < 4; ++j) acc[i][j] = {0.f, 0.f, 0.f, 0.f};

  uint4 ar[4], br[4];
  auto issue = [&](int kc) {
#pragma unroll
    for (int i = 0; i < 4; ++i) {
      int r = (tid >> 3) + i * 32;
      ar[i] = *(const uint4*)(A  + (long)(m0 + r) * K + kc + ro);
      br[i] = *(const uint4*)(Bt + (long)(n0 + r) * K + kc + ro);
    }
  };
  auto commit = [&]() {
#pragma unroll
    for (int i = 0; i < 4; ++i) {
      int r = (tid >> 3) + i * 32;
      *(uint4*)&As[r][ro] = ar[i];
      *(uint4*)&Bs[r][ro] = br[i];
    }
  };

  issue(0);
  const int nk = K >> 6;
  for (int kt = 0; kt < nk; ++kt) {
    commit();
    __syncthreads();
    if (kt + 1 < nk) issue((kt + 1) << 6);
#pragma unroll
    for (int kk = 0; kk < 2; ++kk) {
      bf16x8 af[4], bfr[4];
#pragma unroll
      for (int mt = 0; mt < 4; ++mt)
        af[mt] = *(const bf16x8*)&As[wm * 64 + mt * 16 + l15][kk * 32 + l4 * 8];
#pragma unroll
      for (int nt = 0; nt < 4; ++nt)
        bfr[nt] = *(const bf16x8*)&Bs[wn * 64 + nt * 16 + l15][kk * 32 + l4 * 8];
#pragma unroll
      for (int mt = 0; mt < 4; ++mt)
#pragma unroll
        for (int nt = 0; nt < 4; ++nt)
          acc[mt][nt] = mfma16(af[mt], bfr[nt], acc[mt][nt]);
    }
    __syncthreads();
  }

#pragma unroll
  for (int mt = 0; mt < 4; ++mt)
#pragma unroll
    for (int nt = 0; nt < 4; ++nt)
#pragma unroll
      for (int r = 0; r < 4; ++r) {
        int row = m0 + wm * 64 + mt * 16 + l4 * 4 + r;
        int col = n0 + wn * 64 + nt * 16 + l15;
        float v = acc[mt][nt][r] + bias[col];
        if (EPI == 0) Cf[(long)row * N + col] = v;
        else          Cb[(long)row * N + col] = f2bf(v);
      }
}

// ---------- flash attention: 8 waves (512 thr), QBLK=128, KBLK=64 ----------
// grid (16 qt, 32 bh). Q,K from QKV [4096][3072]; V from Vt packed.
// K/V LDS [64][64] with T2 XOR swizzle (chunk ^= row&7) -> conflict-free b128 reads.
__global__ __launch_bounds__(512) void attn_kernel(
    const u16* __restrict__ QKV, const u16* __restrict__ Vtg,
    const int* __restrict__ maskg, u16* __restrict__ Og)
{
  __shared__ __align__(16) u16 Ks[2][64][64];
  __shared__ __align__(16) u16 Vs[2][64][64];
  __shared__ __align__(16) u16 Ps[128][80];
  const int tid = threadIdx.x, lane = tid & 63, w = tid >> 6;   // w in 0..7
  const int l15 = lane & 15, l4 = lane >> 4;
  const int bh = blockIdx.y, qt = blockIdx.x;
  const int b = bh >> 4, h = bh & 15;
  const u16* Qp = QKV + ((long)(b * SDIM + qt * 128)) * 3072 + h * 192;
  const u16* Kp = QKV + (long)(b * SDIM) * 3072 + h * 192 + 64;
  const u16* Vp = Vtg + (long)bh * HD * SDIM;
  const int* mp = maskg + b * SDIM;
  const float SC = 0.18033688011112042f;   // log2(e) / sqrt(64)

  bf16x8 qa[2];
#pragma unroll
  for (int ks = 0; ks < 2; ++ks)
    qa[ks] = *(const bf16x8*)(Qp + (long)(w * 16 + l15) * 3072 + ks * 32 + l4 * 8);

  f32x4 O[4];
  float mrow[4], lrow[4];
#pragma unroll
  for (int dt = 0; dt < 4; ++dt) O[dt] = {0.f, 0.f, 0.f, 0.f};
#pragma unroll
  for (int r = 0; r < 4; ++r) { mrow[r] = -1e30f; lrow[r] = 0.f; }

  // staging: 512 threads cover one 64x64 tile in one shot
  const int sr = tid >> 3;                 // row 0..63
  const int sc = tid & 7;                  // 16B chunk 0..7
  const int swc = (sc ^ (sr & 7)) << 4;    // swizzled byte offset in row
  char* KsB = (char*)&Ks[0][0][0];
  char* VsB = (char*)&Vs[0][0][0];

  uint4 kr, vr;
  auto issue = [&](int kt2) {
    kr = *(const uint4*)(Kp + (long)(kt2 * 64 + sr) * 3072 + sc * 8);
    vr = *(const uint4*)(Vp + (long)sr * SDIM + kt2 * 64 + sc * 8);
  };
  auto commit = [&](int buf) {
    *(uint4*)(KsB + buf * 8192 + sr * 128 + swc) = kr;
    *(uint4*)(VsB + buf * 8192 + sr * 128 + swc) = vr;
  };

  issue(0); commit(0);
  __syncthreads();

  for (int kt = 0; kt < SDIM / 64; ++kt) {
    const int cur = kt & 1;
    if (kt + 1 < SDIM / 64) issue(kt + 1);

    float mb[4];
#pragma unroll
    for (int nt = 0; nt < 4; ++nt)
      mb[nt] = mp[kt * 64 + nt * 16 + l15] ? 0.f : -1e30f;

    // S = Q K^T (per wave: 16 x 64)
    f32x4 sc4[4];
#pragma unroll
    for (int nt = 0; nt < 4; ++nt) {
      const char* krow = KsB + cur * 8192 + (nt * 16 + l15) * 128;
      bf16x8 kb0 = *(const bf16x8*)(krow + (((0 + l4) ^ (l15 & 7)) << 4));
      bf16x8 kb1 = *(const bf16x8*)(krow + (((4 + l4) ^ (l15 & 7)) << 4));
      f32x4 z = {0.f, 0.f, 0.f, 0.f};
      z = mfma16(qa[0], kb0, z);
      z = mfma16(qa[1], kb1, z);
      sc4[nt] = z;
    }

    // online softmax (exp2 domain) + P -> LDS (bf16)
#pragma unroll
    for (int r = 0; r < 4; ++r) {
      float s0 = sc4[0][r] * SC + mb[0];
      float s1 = sc4[1][r] * SC + mb[1];
      float s2 = sc4[2][r] * SC + mb[2];
      float s3 = sc4[3][r] * SC + mb[3];
      float mx = fmaxf(fmaxf(s0, s1), fmaxf(s2, s3));
#pragma unroll
      for (int off = 1; off < 16; off <<= 1) mx = fmaxf(mx, __shfl_xor(mx, off));
      float mold = mrow[r];
      float mn = fmaxf(mold, mx);
      mrow[r] = mn;
      float p0 = __builtin_amdgcn_exp2f(s0 - mn), p1 = __builtin_amdgcn_exp2f(s1 - mn);
      float p2 = __builtin_amdgcn_exp2f(s2 - mn), p3 = __builtin_amdgcn_exp2f(s3 - mn);
      float rs = p0 + p1 + p2 + p3;
#pragma unroll
      for (int off = 1; off < 16; off <<= 1) rs += __shfl_xor(rs, off);
      if (mx > mold) {
        float al = __builtin_amdgcn_exp2f(mold - mn);
        lrow[r] = lrow[r] * al + rs;
#pragma unroll
        for (int dt = 0; dt < 4; ++dt) O[dt][r] *= al;
      } else {
        lrow[r] += rs;
      }
      int prow = w * 16 + l4 * 4 + r;
      Ps[prow][0 + l15]  = f2bf(p0);
      Ps[prow][16 + l15] = f2bf(p1);
      Ps[prow][32 + l15] = f2bf(p2);
      Ps[prow][48 + l15] = f2bf(p3);
    }
    // P consumed by the same wave only -> lgkmcnt drain, no barrier
    asm volatile("s_waitcnt lgkmcnt(0)" ::: "memory");
    __builtin_amdgcn_sched_barrier(0);

    // O += P V
#pragma unroll
    for (int ks2 = 0; ks2 < 2; ++ks2) {
      bf16x8 pa = *(const bf16x8*)&Ps[w * 16 + l15][ks2 * 32 + l4 * 8];
#pragma unroll
      for (int dt = 0; dt < 4; ++dt) {
        const char* vrow = VsB + cur * 8192 + (dt * 16 + l15) * 128;
        bf16x8 vb = *(const bf16x8*)(vrow + (((ks2 * 4 + l4) ^ (l15 & 7)) << 4));
        O[dt] = mfma16(pa, vb, O[dt]);
      }
    }
    if (kt + 1 < SDIM / 64) commit(cur ^ 1);
    __syncthreads();
  }

#pragma unroll
  for (int dt = 0; dt < 4; ++dt)
#pragma unroll
    for (int r = 0; r < 4; ++r) {
      int s = qt * 128 + w * 16 + l4 * 4 + r;
      int d = dt * 16 + l15;
      float o = O[dt][r] / lrow[r];
      Og[((long)(b * SDIM + s)) * 1024 + h * HD + d] = f2bf(o);
    }
}

extern "C" void kernel_launch(void* const* d_in, const int* in_sizes, int n_in,
                              void* d_out, int out_size, void* d_ws, size_t ws_size,
                              hipStream_t stream) {
  const float* x    = (const float*)d_in[0];
  const int*   am   = (const int*)d_in[1];
  const float* Wqkv = (const float*)d_in[2];
  const float* bqkv = (const float*)d_in[3];
  const float* Wout = (const float*)d_in[4];
  const float* bout = (const float*)d_in[5];
  float* out = (float*)d_out;
  char* ws = (char*)d_ws;

  u16* xb   = (u16*)(ws);                             // 8 MB   x bf16 [4096][1024]
  u16* AOb  = (u16*)(ws);                             // reused after QKV gemm: attn out bf16
  u16* wqt  = (u16*)(ws + (size_t) 8 * 1024 * 1024);  // 6 MB   W_qkv^T bf16 [3072][1024]
  u16* wot  = (u16*)(ws + (size_t)14 * 1024 * 1024);  // 2 MB   W_out^T bf16 [1024][1024]
  u16* QKVb = (u16*)(ws + (size_t)16 * 1024 * 1024);  // 24 MB  qkv bf16 [4096][3072]
  u16* Vtb  = (u16*)(ws + (size_t)40 * 1024 * 1024);  // 8 MB   V^T bf16 [32][64][2048]

  cvt_kernel<<<2048, 256, 0, stream>>>(x, xb, 524288);
  transpose_cvt<<<dim3(96, 32), 256, 0, stream>>>(Wqkv, wqt, 1024, 3072);
  transpose_cvt<<<dim3(32, 32), 256, 0, stream>>>(Wout, wot, 1024, 1024);
  gemm_bf16<1><<<dim3(24, 32), 256, 0, stream>>>(xb, wqt, bqkv, nullptr, QKVb,
                                                 4096, 3072, 1024);
  vtrans_kernel<<<dim3(32, 32), 256, 0, stream>>>(QKVb, Vtb);
  attn_kernel<<<dim3(16, 32), 512, 0, stream>>>(QKVb, Vtb, am, AOb);
  gemm_bf16<0><<<dim3(8, 32), 256, 0, stream>>>(AOb, wot, bout, out, nullptr,
                                                4096, 1024, 1024);
}

// Round 5
// 197.254 us; speedup vs baseline: 1.9615x; 1.4770x over previous
//
#include <hip/hip_runtime.h>

#define SDIM 2048
#define NHEADS 16
#define HD 64

typedef __attribute__((ext_vector_type(8))) short bf16x8;
typedef __attribute__((ext_vector_type(8))) unsigned short u16x8;
typedef __attribute__((ext_vector_type(4))) float f32x4;
typedef unsigned short u16;

static __device__ __forceinline__ u16 f2bf(float f) {
  unsigned u = __builtin_bit_cast(unsigned, f);
  u += 0x7fffu + ((u >> 16) & 1u);   // RNE
  return (u16)(u >> 16);
}

static __device__ __forceinline__ f32x4 mfma16(bf16x8 a, bf16x8 b, f32x4 c) {
  return __builtin_amdgcn_mfma_f32_16x16x32_bf16(a, b, c, 0, 0, 0);
}

// async global->LDS, 16B per lane; LDS dest is wave-uniform base + lane*16
static __device__ __forceinline__ void gload16(const u16* g, u16* l) {
  __builtin_amdgcn_global_load_lds(
      (const __attribute__((address_space(1))) void*)g,
      (__attribute__((address_space(3))) void*)l, 16, 0, 0);
}

// ---------- prep: fp32 -> bf16, 8 elems/thread ----------
__global__ void cvt_kernel(const float* __restrict__ in, u16* __restrict__ out, int n8) {
  int i = blockIdx.x * blockDim.x + threadIdx.x;
  if (i >= n8) return;
  const float4* p = (const float4*)(in + (long)i * 8);
  float4 a = p[0], b = p[1];
  u16x8 r;
  r[0] = f2bf(a.x); r[1] = f2bf(a.y); r[2] = f2bf(a.z); r[3] = f2bf(a.w);
  r[4] = f2bf(b.x); r[5] = f2bf(b.y); r[6] = f2bf(b.z); r[7] = f2bf(b.w);
  *(u16x8*)(out + (long)i * 8) = r;
}

// ---------- prep: W [K][N] fp32 -> Wt [N][K] bf16 ----------
__global__ void transpose_cvt(const float* __restrict__ W, u16* __restrict__ Wt, int K, int N) {
  __shared__ float t[32][33];
  int tx = threadIdx.x & 31, ty = threadIdx.x >> 5;   // 32 x 8
  int n0 = blockIdx.x * 32, k0 = blockIdx.y * 32;
#pragma unroll
  for (int i = 0; i < 32; i += 8) t[ty + i][tx] = W[(long)(k0 + ty + i) * N + n0 + tx];
  __syncthreads();
#pragma unroll
  for (int i = 0; i < 32; i += 8) Wt[(long)(n0 + ty + i) * K + k0 + tx] = f2bf(t[tx][ty + i]);
}

// ---------- V part of QKV [4096][3072] -> Vt [32][64][2048] bf16 ----------
__global__ __launch_bounds__(256) void vtrans_kernel(const u16* __restrict__ QKV,
                                                     u16* __restrict__ Vt) {
  __shared__ u16 t[64][72];
  const int bh = blockIdx.y, s0 = blockIdx.x * 64;
  const int b = bh >> 4, h = bh & 15;
  const u16* src = QKV + ((long)(b * SDIM + s0)) * 3072 + h * 192 + 128;
  int r = threadIdx.x >> 3, c = (threadIdx.x & 7) * 8;
  *(uint4*)&t[r][c]      = *(const uint4*)(src + (long)r * 3072 + c);
  *(uint4*)&t[r + 32][c] = *(const uint4*)(src + (long)(r + 32) * 3072 + c);
  __syncthreads();
  int d = threadIdx.x >> 2, sc = (threadIdx.x & 3) * 16;
  u16 tmp[16];
#pragma unroll
  for (int k = 0; k < 16; ++k) tmp[k] = t[sc + k][d];
  u16* dst = Vt + ((long)(bh * HD + d)) * SDIM + s0 + sc;
  *(uint4*)dst = *(uint4*)&tmp[0];
  *(uint4*)(dst + 8) = *(uint4*)&tmp[8];
}

// ---------- bf16 GEMM, 128x128x64 tile, 4 waves, global_load_lds staging ----------
// LDS linear [128][64]; global source chunk pre-swizzled (c ^= row&7); reads apply same XOR.
template <int EPI>
__global__ __launch_bounds__(256) void gemm_bf16(
    const u16* __restrict__ A, const u16* __restrict__ Bt,
    const float* __restrict__ bias, float* __restrict__ Cf, u16* __restrict__ Cb,
    int M, int N, int K)
{
  __shared__ __align__(16) u16 As[128 * 64];
  __shared__ __align__(16) u16 Bs[128 * 64];
  const int tid = threadIdx.x, lane = tid & 63, wid = tid >> 6;
  const int wm = wid >> 1, wn = wid & 1;
  const int l15 = lane & 15, l4 = lane >> 4;
  const int m0 = blockIdx.y * 128, n0 = blockIdx.x * 128;
  const int srow = lane >> 3;                 // 0..7 row within 8-row group
  const int schunk = (lane & 7) ^ srow;       // swizzled source 16B-chunk

  f32x4 acc[4][4];
#pragma unroll
  for (int i = 0; i < 4; ++i)
#pragma unroll
    for (int j = 0; j < 4; ++j) acc[i][j] = {0.f, 0.f, 0.f, 0.f};

  const int nk = K >> 6;
  for (int kt = 0; kt < nk; ++kt) {
    const int kc = kt << 6;
    // stage: wave wid covers rows [wid*32, wid*32+32) of both tiles; 8 rows per issue
#pragma unroll
    for (int is = 0; is < 4; ++is) {
      int rb = wid * 32 + is * 8;
      int r = rb + srow;
      gload16(A  + (long)(m0 + r) * K + kc + schunk * 8, &As[rb * 64]);
      gload16(Bt + (long)(n0 + r) * K + kc + schunk * 8, &Bs[rb * 64]);
    }
    asm volatile("s_waitcnt vmcnt(0)" ::: "memory");
    __syncthreads();
#pragma unroll
    for (int kk = 0; kk < 2; ++kk) {
      bf16x8 af[4], bfr[4];
#pragma unroll
      for (int mt = 0; mt < 4; ++mt) {
        int row = wm * 64 + mt * 16 + l15;
        af[mt] = *(const bf16x8*)&As[row * 64 + (((kk * 4 + l4) ^ (l15 & 7)) * 8)];
      }
#pragma unroll
      for (int nt = 0; nt < 4; ++nt) {
        int row = wn * 64 + nt * 16 + l15;
        bfr[nt] = *(const bf16x8*)&Bs[row * 64 + (((kk * 4 + l4) ^ (l15 & 7)) * 8)];
      }
#pragma unroll
      for (int mt = 0; mt < 4; ++mt)
#pragma unroll
        for (int nt = 0; nt < 4; ++nt)
          acc[mt][nt] = mfma16(af[mt], bfr[nt], acc[mt][nt]);
    }
    __syncthreads();
  }

#pragma unroll
  for (int mt = 0; mt < 4; ++mt)
#pragma unroll
    for (int nt = 0; nt < 4; ++nt)
#pragma unroll
      for (int r = 0; r < 4; ++r) {
        int row = m0 + wm * 64 + mt * 16 + l4 * 4 + r;
        int col = n0 + wn * 64 + nt * 16 + l15;
        float v = acc[mt][nt][r] + bias[col];
        if (EPI == 0) Cf[(long)row * N + col] = v;
        else          Cb[(long)row * N + col] = f2bf(v);
      }
}

// ---------- flash attention: 8 waves (512 thr), QBLK=128, KBLK=64 ----------
// grid (16 qt, 32 bh). Q,K from QKV [4096][3072]; V from Vt packed.
// K/V LDS [64][64], double-buffered, staged via global_load_lds with source XOR swizzle.
__global__ __launch_bounds__(512) void attn_kernel(
    const u16* __restrict__ QKV, const u16* __restrict__ Vtg,
    const int* __restrict__ maskg, u16* __restrict__ Og)
{
  __shared__ __align__(16) u16 Ks[2][64][64];
  __shared__ __align__(16) u16 Vs[2][64][64];
  __shared__ __align__(16) u16 Ps[128][80];
  const int tid = threadIdx.x, lane = tid & 63, w = tid >> 6;   // w in 0..7
  const int l15 = lane & 15, l4 = lane >> 4;
  const int bh = blockIdx.y, qt = blockIdx.x;
  const int b = bh >> 4, h = bh & 15;
  const u16* Qp = QKV + ((long)(b * SDIM + qt * 128)) * 3072 + h * 192;
  const u16* Kp = QKV + (long)(b * SDIM) * 3072 + h * 192 + 64;
  const u16* Vp = Vtg + (long)bh * HD * SDIM;
  const int* mp = maskg + b * SDIM;
  const float SC = 0.18033688011112042f;   // log2(e) / sqrt(64)

  bf16x8 qa[2];
#pragma unroll
  for (int ks = 0; ks < 2; ++ks)
    qa[ks] = *(const bf16x8*)(Qp + (long)(w * 16 + l15) * 3072 + ks * 32 + l4 * 8);

  f32x4 O[4];
  float mrow[4], lrow[4];
#pragma unroll
  for (int dt = 0; dt < 4; ++dt) O[dt] = {0.f, 0.f, 0.f, 0.f};
#pragma unroll
  for (int r = 0; r < 4; ++r) { mrow[r] = -1e30f; lrow[r] = 0.f; }

  char* KsB = (char*)&Ks[0][0][0];
  char* VsB = (char*)&Vs[0][0][0];
  const int srow = lane >> 3;                // row within wave's 8-row group
  const int schunk = (lane & 7) ^ srow;      // swizzled source chunk

  // wave w stages rows [w*8, w*8+8) of K and V for one 64x64 tile
  auto stage = [&](int kt2, int buf) {
    int row = w * 8 + srow;
    gload16(Kp + (long)(kt2 * 64 + row) * 3072 + schunk * 8,
            (u16*)(KsB + buf * 8192 + (w * 8) * 128));
    gload16(Vp + (long)row * SDIM + kt2 * 64 + schunk * 8,
            (u16*)(VsB + buf * 8192 + (w * 8) * 128));
  };

  stage(0, 0);
  asm volatile("s_waitcnt vmcnt(0)" ::: "memory");
  __syncthreads();

  for (int kt = 0; kt < SDIM / 64; ++kt) {
    const int cur = kt & 1;
    if (kt + 1 < SDIM / 64) stage(kt + 1, cur ^ 1);   // DMA flies under compute

    float mb[4];
#pragma unroll
    for (int nt = 0; nt < 4; ++nt)
      mb[nt] = mp[kt * 64 + nt * 16 + l15] ? 0.f : -1e30f;

    // S = Q K^T (per wave: 16 x 64)
    f32x4 sc4[4];
#pragma unroll
    for (int nt = 0; nt < 4; ++nt) {
      const char* krow = KsB + cur * 8192 + (nt * 16 + l15) * 128;
      bf16x8 kb0 = *(const bf16x8*)(krow + (((0 + l4) ^ (l15 & 7)) << 4));
      bf16x8 kb1 = *(const bf16x8*)(krow + (((4 + l4) ^ (l15 & 7)) << 4));
      f32x4 z = {0.f, 0.f, 0.f, 0.f};
      z = mfma16(qa[0], kb0, z);
      z = mfma16(qa[1], kb1, z);
      sc4[nt] = z;
    }

    // online softmax (exp2 domain) + P -> LDS (bf16)
#pragma unroll
    for (int r = 0; r < 4; ++r) {
      float s0 = sc4[0][r] * SC + mb[0];
      float s1 = sc4[1][r] * SC + mb[1];
      float s2 = sc4[2][r] * SC + mb[2];
      float s3 = sc4[3][r] * SC + mb[3];
      float mx = fmaxf(fmaxf(s0, s1), fmaxf(s2, s3));
#pragma unroll
      for (int off = 1; off < 16; off <<= 1) mx = fmaxf(mx, __shfl_xor(mx, off));
      float mold = mrow[r];
      float mn = fmaxf(mold, mx);
      mrow[r] = mn;
      float p0 = __builtin_amdgcn_exp2f(s0 - mn), p1 = __builtin_amdgcn_exp2f(s1 - mn);
      float p2 = __builtin_amdgcn_exp2f(s2 - mn), p3 = __builtin_amdgcn_exp2f(s3 - mn);
      float rs = p0 + p1 + p2 + p3;
#pragma unroll
      for (int off = 1; off < 16; off <<= 1) rs += __shfl_xor(rs, off);
      if (mx > mold) {
        float al = __builtin_amdgcn_exp2f(mold - mn);
        lrow[r] = lrow[r] * al + rs;
#pragma unroll
        for (int dt = 0; dt < 4; ++dt) O[dt][r] *= al;
      } else {
        lrow[r] += rs;
      }
      int prow = w * 16 + l4 * 4 + r;
      Ps[prow][0 + l15]  = f2bf(p0);
      Ps[prow][16 + l15] = f2bf(p1);
      Ps[prow][32 + l15] = f2bf(p2);
      Ps[prow][48 + l15] = f2bf(p3);
    }
    // P consumed by the same wave only -> lgkmcnt drain, no barrier
    asm volatile("s_waitcnt lgkmcnt(0)" ::: "memory");
    __builtin_amdgcn_sched_barrier(0);

    // O += P V
#pragma unroll
    for (int ks2 = 0; ks2 < 2; ++ks2) {
      bf16x8 pa = *(const bf16x8*)&Ps[w * 16 + l15][ks2 * 32 + l4 * 8];
#pragma unroll
      for (int dt = 0; dt < 4; ++dt) {
        const char* vrow = VsB + cur * 8192 + (dt * 16 + l15) * 128;
        bf16x8 vb = *(const bf16x8*)(vrow + (((ks2 * 4 + l4) ^ (l15 & 7)) << 4));
        O[dt] = mfma16(pa, vb, O[dt]);
      }
    }
    __syncthreads();   // drains prefetch vmcnt + syncs buffers (one barrier per tile)
  }

#pragma unroll
  for (int dt = 0; dt < 4; ++dt)
#pragma unroll
    for (int r = 0; r < 4; ++r) {
      int s = qt * 128 + w * 16 + l4 * 4 + r;
      int d = dt * 16 + l15;
      float o = O[dt][r] / lrow[r];
      Og[((long)(b * SDIM + s)) * 1024 + h * HD + d] = f2bf(o);
    }
}

extern "C" void kernel_launch(void* const* d_in, const int* in_sizes, int n_in,
                              void* d_out, int out_size, void* d_ws, size_t ws_size,
                              hipStream_t stream) {
  const float* x    = (const float*)d_in[0];
  const int*   am   = (const int*)d_in[1];
  const float* Wqkv = (const float*)d_in[2];
  const float* bqkv = (const float*)d_in[3];
  const float* Wout = (const float*)d_in[4];
  const float* bout = (const float*)d_in[5];
  float* out = (float*)d_out;
  char* ws = (char*)d_ws;

  u16* xb   = (u16*)(ws);                             // 8 MB   x bf16 [4096][1024]
  u16* AOb  = (u16*)(ws);                             // reused after QKV gemm: attn out bf16
  u16* wqt  = (u16*)(ws + (size_t) 8 * 1024 * 1024);  // 6 MB   W_qkv^T bf16 [3072][1024]
  u16* wot  = (u16*)(ws + (size_t)14 * 1024 * 1024);  // 2 MB   W_out^T bf16 [1024][1024]
  u16* QKVb = (u16*)(ws + (size_t)16 * 1024 * 1024);  // 24 MB  qkv bf16 [4096][3072]
  u16* Vtb  = (u16*)(ws + (size_t)40 * 1024 * 1024);  // 8 MB   V^T bf16 [32][64][2048]

  cvt_kernel<<<2048, 256, 0, stream>>>(x, xb, 524288);
  transpose_cvt<<<dim3(96, 32), 256, 0, stream>>>(Wqkv, wqt, 1024, 3072);
  transpose_cvt<<<dim3(32, 32), 256, 0, stream>>>(Wout, wot, 1024, 1024);
  gemm_bf16<1><<<dim3(24, 32), 256, 0, stream>>>(xb, wqt, bqkv, nullptr, QKVb,
                                                 4096, 3072, 1024);
  vtrans_kernel<<<dim3(32, 32), 256, 0, stream>>>(QKVb, Vtb);
  attn_kernel<<<dim3(16, 32), 512, 0, stream>>>(QKVb, Vtb, am, AOb);
  gemm_bf16<0><<<dim3(8, 32), 256, 0, stream>>>(AOb, wot, bout, out, nullptr,
                                                4096, 1024, 1024);
}

// Round 6
// 146.035 us; speedup vs baseline: 2.6495x; 1.3507x over previous
//
#include <hip/hip_runtime.h>

#define SDIM 2048
#define NHEADS 16
#define HD 64

typedef __attribute__((ext_vector_type(8))) short bf16x8;
typedef __attribute__((ext_vector_type(8))) unsigned short u16x8;
typedef __attribute__((ext_vector_type(4))) float f32x4;
typedef unsigned short u16;

static __device__ __forceinline__ u16 f2bf(float f) {
  unsigned u = __builtin_bit_cast(unsigned, f);
  u += 0x7fffu + ((u >> 16) & 1u);   // RNE
  return (u16)(u >> 16);
}

static __device__ __forceinline__ f32x4 mfma16(bf16x8 a, bf16x8 b, f32x4 c) {
  return __builtin_amdgcn_mfma_f32_16x16x32_bf16(a, b, c, 0, 0, 0);
}

// async global->LDS, 16B per lane; LDS dest is wave-uniform base + lane*16
static __device__ __forceinline__ void gload16(const u16* g, u16* l) {
  __builtin_amdgcn_global_load_lds(
      (const __attribute__((address_space(1))) void*)g,
      (__attribute__((address_space(3))) void*)l, 16, 0, 0);
}

// ---------- prep: fp32 -> bf16, 8 elems/thread ----------
__global__ void cvt_kernel(const float* __restrict__ in, u16* __restrict__ out, int n8) {
  int i = blockIdx.x * blockDim.x + threadIdx.x;
  if (i >= n8) return;
  const float4* p = (const float4*)(in + (long)i * 8);
  float4 a = p[0], b = p[1];
  u16x8 r;
  r[0] = f2bf(a.x); r[1] = f2bf(a.y); r[2] = f2bf(a.z); r[3] = f2bf(a.w);
  r[4] = f2bf(b.x); r[5] = f2bf(b.y); r[6] = f2bf(b.z); r[7] = f2bf(b.w);
  *(u16x8*)(out + (long)i * 8) = r;
}

// ---------- prep: W [K][N] fp32 -> Wt [N][K] bf16 ----------
__global__ void transpose_cvt(const float* __restrict__ W, u16* __restrict__ Wt, int K, int N) {
  __shared__ float t[32][33];
  int tx = threadIdx.x & 31, ty = threadIdx.x >> 5;   // 32 x 8
  int n0 = blockIdx.x * 32, k0 = blockIdx.y * 32;
#pragma unroll
  for (int i = 0; i < 32; i += 8) t[ty + i][tx] = W[(long)(k0 + ty + i) * N + n0 + tx];
  __syncthreads();
#pragma unroll
  for (int i = 0; i < 32; i += 8) Wt[(long)(n0 + ty + i) * K + k0 + tx] = f2bf(t[tx][ty + i]);
}

// ---------- V part of QKV [4096][3072] -> Vt [32][64][2048] bf16 ----------
__global__ __launch_bounds__(256) void vtrans_kernel(const u16* __restrict__ QKV,
                                                     u16* __restrict__ Vt) {
  __shared__ u16 t[64][72];
  const int bh = blockIdx.y, s0 = blockIdx.x * 64;
  const int b = bh >> 4, h = bh & 15;
  const u16* src = QKV + ((long)(b * SDIM + s0)) * 3072 + h * 192 + 128;
  int r = threadIdx.x >> 3, c = (threadIdx.x & 7) * 8;
  *(uint4*)&t[r][c]      = *(const uint4*)(src + (long)r * 3072 + c);
  *(uint4*)&t[r + 32][c] = *(const uint4*)(src + (long)(r + 32) * 3072 + c);
  __syncthreads();
  int d = threadIdx.x >> 2, sc = (threadIdx.x & 3) * 16;
  u16 tmp[16];
#pragma unroll
  for (int k = 0; k < 16; ++k) tmp[k] = t[sc + k][d];
  u16* dst = Vt + ((long)(bh * HD + d)) * SDIM + s0 + sc;
  *(uint4*)dst = *(uint4*)&tmp[0];
  *(uint4*)(dst + 8) = *(uint4*)&tmp[8];
}

// ---------- bf16 GEMM, 128x128x64 tile, 4 waves, global_load_lds staging ----------
template <int EPI>
__global__ __launch_bounds__(256) void gemm_bf16(
    const u16* __restrict__ A, const u16* __restrict__ Bt,
    const float* __restrict__ bias, float* __restrict__ Cf, u16* __restrict__ Cb,
    int M, int N, int K)
{
  __shared__ __align__(16) u16 As[128 * 64];
  __shared__ __align__(16) u16 Bs[128 * 64];
  const int tid = threadIdx.x, lane = tid & 63, wid = tid >> 6;
  const int wm = wid >> 1, wn = wid & 1;
  const int l15 = lane & 15, l4 = lane >> 4;
  const int m0 = blockIdx.y * 128, n0 = blockIdx.x * 128;
  const int srow = lane >> 3;
  const int schunk = (lane & 7) ^ srow;

  f32x4 acc[4][4];
#pragma unroll
  for (int i = 0; i < 4; ++i)
#pragma unroll
    for (int j = 0; j < 4; ++j) acc[i][j] = {0.f, 0.f, 0.f, 0.f};

  const int nk = K >> 6;
  for (int kt = 0; kt < nk; ++kt) {
    const int kc = kt << 6;
#pragma unroll
    for (int is = 0; is < 4; ++is) {
      int rb = wid * 32 + is * 8;
      int r = rb + srow;
      gload16(A  + (long)(m0 + r) * K + kc + schunk * 8, &As[rb * 64]);
      gload16(Bt + (long)(n0 + r) * K + kc + schunk * 8, &Bs[rb * 64]);
    }
    asm volatile("s_waitcnt vmcnt(0)" ::: "memory");
    __syncthreads();
#pragma unroll
    for (int kk = 0; kk < 2; ++kk) {
      bf16x8 af[4], bfr[4];
#pragma unroll
      for (int mt = 0; mt < 4; ++mt) {
        int row = wm * 64 + mt * 16 + l15;
        af[mt] = *(const bf16x8*)&As[row * 64 + (((kk * 4 + l4) ^ (l15 & 7)) * 8)];
      }
#pragma unroll
      for (int nt = 0; nt < 4; ++nt) {
        int row = wn * 64 + nt * 16 + l15;
        bfr[nt] = *(const bf16x8*)&Bs[row * 64 + (((kk * 4 + l4) ^ (l15 & 7)) * 8)];
      }
#pragma unroll
      for (int mt = 0; mt < 4; ++mt)
#pragma unroll
        for (int nt = 0; nt < 4; ++nt)
          acc[mt][nt] = mfma16(af[mt], bfr[nt], acc[mt][nt]);
    }
    __syncthreads();
  }

#pragma unroll
  for (int mt = 0; mt < 4; ++mt)
#pragma unroll
    for (int nt = 0; nt < 4; ++nt)
#pragma unroll
      for (int r = 0; r < 4; ++r) {
        int row = m0 + wm * 64 + mt * 16 + l4 * 4 + r;
        int col = n0 + wn * 64 + nt * 16 + l15;
        float v = acc[mt][nt][r] + bias[col];
        if (EPI == 0) Cf[(long)row * N + col] = v;
        else          Cb[(long)row * N + col] = f2bf(v);
      }
}

// ---------- flash attention: 8 waves (512 thr), QBLK=128, KBLK=64 ----------
// Static-max softmax (M=12): no per-tile max/sum butterflies, no rescale.
// Denominator recovered by one 16-lane butterfly after the k-loop.
// K/V/P all in XOR-swizzled [.][64] LDS tiles (conflict-free b128).
__global__ __launch_bounds__(512) void attn_kernel(
    const u16* __restrict__ QKV, const u16* __restrict__ Vtg,
    const int* __restrict__ maskg, u16* __restrict__ Og)
{
  __shared__ __align__(16) u16 Ks[2][64][64];
  __shared__ __align__(16) u16 Vs[2][64][64];
  __shared__ __align__(16) u16 Ps[128][64];
  const int tid = threadIdx.x, lane = tid & 63, w = tid >> 6;   // w in 0..7
  const int l15 = lane & 15, l4 = lane >> 4;
  const int bh = blockIdx.y, qt = blockIdx.x;
  const int b = bh >> 4, h = bh & 15;
  const u16* Qp = QKV + ((long)(b * SDIM + qt * 128)) * 3072 + h * 192;
  const u16* Kp = QKV + (long)(b * SDIM) * 3072 + h * 192 + 64;
  const u16* Vp = Vtg + (long)bh * HD * SDIM;
  const int* mp = maskg + b * SDIM;
  const float SC = 0.18033688011112042f;   // log2(e) / sqrt(64)

  bf16x8 qa[2];
#pragma unroll
  for (int ks = 0; ks < 2; ++ks)
    qa[ks] = *(const bf16x8*)(Qp + (long)(w * 16 + l15) * 3072 + ks * 32 + l4 * 8);

  f32x4 O[4];
  float lsum[4];
#pragma unroll
  for (int dt = 0; dt < 4; ++dt) O[dt] = {0.f, 0.f, 0.f, 0.f};
#pragma unroll
  for (int r = 0; r < 4; ++r) lsum[r] = 0.f;

  char* KsB = (char*)&Ks[0][0][0];
  char* VsB = (char*)&Vs[0][0][0];
  char* PsB = (char*)&Ps[0][0];
  const int srow = lane >> 3;
  const int schunk = (lane & 7) ^ srow;

  auto stage = [&](int kt2, int buf) {
    int row = w * 8 + srow;
    gload16(Kp + (long)(kt2 * 64 + row) * 3072 + schunk * 8,
            (u16*)(KsB + buf * 8192 + (w * 8) * 128));
    gload16(Vp + (long)row * SDIM + kt2 * 64 + schunk * 8,
            (u16*)(VsB + buf * 8192 + (w * 8) * 128));
  };

  stage(0, 0);
  asm volatile("s_waitcnt vmcnt(0)" ::: "memory");
  __syncthreads();

  for (int kt = 0; kt < SDIM / 64; ++kt) {
    const int cur = kt & 1;
    if (kt + 1 < SDIM / 64) stage(kt + 1, cur ^ 1);   // DMA flies under compute

    float mbM[4];
#pragma unroll
    for (int nt = 0; nt < 4; ++nt)
      mbM[nt] = (mp[kt * 64 + nt * 16 + l15] ? 0.f : -1e30f) - 12.0f;  // mask bias - static max

    // S = Q K^T (per wave: 16 x 64)
    f32x4 sc4[4];
#pragma unroll
    for (int nt = 0; nt < 4; ++nt) {
      const char* krow = KsB + cur * 8192 + (nt * 16 + l15) * 128;
      bf16x8 kb0 = *(const bf16x8*)(krow + (((0 + l4) ^ (l15 & 7)) << 4));
      bf16x8 kb1 = *(const bf16x8*)(krow + (((4 + l4) ^ (l15 & 7)) << 4));
      f32x4 z = {0.f, 0.f, 0.f, 0.f};
      z = mfma16(qa[0], kb0, z);
      z = mfma16(qa[1], kb1, z);
      sc4[nt] = z;
    }

    // static-max softmax: P = exp2(s*SC + mb - 12); per-lane partial row-sum
#pragma unroll
    for (int r = 0; r < 4; ++r) {
      float p0 = __builtin_amdgcn_exp2f(sc4[0][r] * SC + mbM[0]);
      float p1 = __builtin_amdgcn_exp2f(sc4[1][r] * SC + mbM[1]);
      float p2 = __builtin_amdgcn_exp2f(sc4[2][r] * SC + mbM[2]);
      float p3 = __builtin_amdgcn_exp2f(sc4[3][r] * SC + mbM[3]);
      lsum[r] += (p0 + p1) + (p2 + p3);
      int prow = w * 16 + l4 * 4 + r;
      int rbase = prow * 128, rx = prow & 7;
      *(u16*)(PsB + rbase + (((0 + (l15 >> 3)) ^ rx) << 4) + (l15 & 7) * 2) = f2bf(p0);
      *(u16*)(PsB + rbase + (((2 + (l15 >> 3)) ^ rx) << 4) + (l15 & 7) * 2) = f2bf(p1);
      *(u16*)(PsB + rbase + (((4 + (l15 >> 3)) ^ rx) << 4) + (l15 & 7) * 2) = f2bf(p2);
      *(u16*)(PsB + rbase + (((6 + (l15 >> 3)) ^ rx) << 4) + (l15 & 7) * 2) = f2bf(p3);
    }
    // P consumed by the same wave only -> lgkmcnt drain, no barrier
    asm volatile("s_waitcnt lgkmcnt(0)" ::: "memory");
    __builtin_amdgcn_sched_barrier(0);

    // O += P V
#pragma unroll
    for (int ks2 = 0; ks2 < 2; ++ks2) {
      bf16x8 pa = *(const bf16x8*)(PsB + (w * 16 + l15) * 128 + (((ks2 * 4 + l4) ^ (l15 & 7)) << 4));
#pragma unroll
      for (int dt = 0; dt < 4; ++dt) {
        const char* vrow = VsB + cur * 8192 + (dt * 16 + l15) * 128;
        bf16x8 vb = *(const bf16x8*)(vrow + (((ks2 * 4 + l4) ^ (l15 & 7)) << 4));
        O[dt] = mfma16(pa, vb, O[dt]);
      }
    }
    __syncthreads();   // drains prefetch vmcnt + syncs buffers (one barrier per tile)
  }

  // one butterfly at the end recovers each row's denominator
  float inv[4];
#pragma unroll
  for (int r = 0; r < 4; ++r) {
    float s = lsum[r];
#pragma unroll
    for (int off = 1; off < 16; off <<= 1) s += __shfl_xor(s, off);
    inv[r] = 1.0f / s;
  }

#pragma unroll
  for (int dt = 0; dt < 4; ++dt)
#pragma unroll
    for (int r = 0; r < 4; ++r) {
      int s = qt * 128 + w * 16 + l4 * 4 + r;
      int d = dt * 16 + l15;
      Og[((long)(b * SDIM + s)) * 1024 + h * HD + d] = f2bf(O[dt][r] * inv[r]);
    }
}

extern "C" void kernel_launch(void* const* d_in, const int* in_sizes, int n_in,
                              void* d_out, int out_size, void* d_ws, size_t ws_size,
                              hipStream_t stream) {
  const float* x    = (const float*)d_in[0];
  const int*   am   = (const int*)d_in[1];
  const float* Wqkv = (const float*)d_in[2];
  const float* bqkv = (const float*)d_in[3];
  const float* Wout = (const float*)d_in[4];
  const float* bout = (const float*)d_in[5];
  float* out = (float*)d_out;
  char* ws = (char*)d_ws;

  u16* xb   = (u16*)(ws);                             // 8 MB   x bf16 [4096][1024]
  u16* AOb  = (u16*)(ws);                             // reused after QKV gemm: attn out bf16
  u16* wqt  = (u16*)(ws + (size_t) 8 * 1024 * 1024);  // 6 MB   W_qkv^T bf16 [3072][1024]
  u16* wot  = (u16*)(ws + (size_t)14 * 1024 * 1024);  // 2 MB   W_out^T bf16 [1024][1024]
  u16* QKVb = (u16*)(ws + (size_t)16 * 1024 * 1024);  // 24 MB  qkv bf16 [4096][3072]
  u16* Vtb  = (u16*)(ws + (size_t)40 * 1024 * 1024);  // 8 MB   V^T bf16 [32][64][2048]

  cvt_kernel<<<2048, 256, 0, stream>>>(x, xb, 524288);
  transpose_cvt<<<dim3(96, 32), 256, 0, stream>>>(Wqkv, wqt, 1024, 3072);
  transpose_cvt<<<dim3(32, 32), 256, 0, stream>>>(Wout, wot, 1024, 1024);
  gemm_bf16<1><<<dim3(24, 32), 256, 0, stream>>>(xb, wqt, bqkv, nullptr, QKVb,
                                                 4096, 3072, 1024);
  vtrans_kernel<<<dim3(32, 32), 256, 0, stream>>>(QKVb, Vtb);
  attn_kernel<<<dim3(16, 32), 512, 0, stream>>>(QKVb, Vtb, am, AOb);
  gemm_bf16<0><<<dim3(8, 32), 256, 0, stream>>>(AOb, wot, bout, out, nullptr,
                                                4096, 1024, 1024);
}

// Round 7
// 141.367 us; speedup vs baseline: 2.7370x; 1.0330x over previous
//
#include <hip/hip_runtime.h>

#define SDIM 2048
#define NHEADS 16
#define HD 64

typedef __attribute__((ext_vector_type(8))) short bf16x8;
typedef __attribute__((ext_vector_type(8))) unsigned short u16x8;
typedef __attribute__((ext_vector_type(4))) float f32x4;
typedef unsigned short u16;

static __device__ __forceinline__ u16 f2bf(float f) {
  unsigned u = __builtin_bit_cast(unsigned, f);
  u += 0x7fffu + ((u >> 16) & 1u);   // RNE
  return (u16)(u >> 16);
}

// pack two f32 -> two bf16 in one instruction (no builtin on gfx950)
static __device__ __forceinline__ unsigned cvt_pk_bf16(float lo, float hi) {
  unsigned r;
  asm("v_cvt_pk_bf16_f32 %0, %1, %2" : "=v"(r) : "v"(lo), "v"(hi));
  return r;
}

static __device__ __forceinline__ f32x4 mfma16(bf16x8 a, bf16x8 b, f32x4 c) {
  return __builtin_amdgcn_mfma_f32_16x16x32_bf16(a, b, c, 0, 0, 0);
}

// async global->LDS, 16B per lane; LDS dest is wave-uniform base + lane*16
static __device__ __forceinline__ void gload16(const u16* g, u16* l) {
  __builtin_amdgcn_global_load_lds(
      (const __attribute__((address_space(1))) void*)g,
      (__attribute__((address_space(3))) void*)l, 16, 0, 0);
}

// ---------- prep: fp32 -> bf16, 8 elems/thread ----------
__global__ void cvt_kernel(const float* __restrict__ in, u16* __restrict__ out, int n8) {
  int i = blockIdx.x * blockDim.x + threadIdx.x;
  if (i >= n8) return;
  const float4* p = (const float4*)(in + (long)i * 8);
  float4 a = p[0], b = p[1];
  u16x8 r;
  r[0] = f2bf(a.x); r[1] = f2bf(a.y); r[2] = f2bf(a.z); r[3] = f2bf(a.w);
  r[4] = f2bf(b.x); r[5] = f2bf(b.y); r[6] = f2bf(b.z); r[7] = f2bf(b.w);
  *(u16x8*)(out + (long)i * 8) = r;
}

// ---------- prep: W [K][N] fp32 -> Wt [N][K] bf16 ----------
__global__ void transpose_cvt(const float* __restrict__ W, u16* __restrict__ Wt, int K, int N) {
  __shared__ float t[32][33];
  int tx = threadIdx.x & 31, ty = threadIdx.x >> 5;   // 32 x 8
  int n0 = blockIdx.x * 32, k0 = blockIdx.y * 32;
#pragma unroll
  for (int i = 0; i < 32; i += 8) t[ty + i][tx] = W[(long)(k0 + ty + i) * N + n0 + tx];
  __syncthreads();
#pragma unroll
  for (int i = 0; i < 32; i += 8) Wt[(long)(n0 + ty + i) * K + k0 + tx] = f2bf(t[tx][ty + i]);
}

// ---------- V part of QKV [4096][3072] -> Vt [32][64][2048] bf16 ----------
__global__ __launch_bounds__(256) void vtrans_kernel(const u16* __restrict__ QKV,
                                                     u16* __restrict__ Vt) {
  __shared__ u16 t[64][72];
  const int bh = blockIdx.y, s0 = blockIdx.x * 64;
  const int b = bh >> 4, h = bh & 15;
  const u16* src = QKV + ((long)(b * SDIM + s0)) * 3072 + h * 192 + 128;
  int r = threadIdx.x >> 3, c = (threadIdx.x & 7) * 8;
  *(uint4*)&t[r][c]      = *(const uint4*)(src + (long)r * 3072 + c);
  *(uint4*)&t[r + 32][c] = *(const uint4*)(src + (long)(r + 32) * 3072 + c);
  __syncthreads();
  int d = threadIdx.x >> 2, sc = (threadIdx.x & 3) * 16;
  u16 tmp[16];
#pragma unroll
  for (int k = 0; k < 16; ++k) tmp[k] = t[sc + k][d];
  u16* dst = Vt + ((long)(bh * HD + d)) * SDIM + s0 + sc;
  *(uint4*)dst = *(uint4*)&tmp[0];
  *(uint4*)(dst + 8) = *(uint4*)&tmp[8];
}

// ---------- bf16 GEMM, 128x128x64 tile, 4 waves, global_load_lds staging ----------
template <int EPI>
__global__ __launch_bounds__(256) void gemm_bf16(
    const u16* __restrict__ A, const u16* __restrict__ Bt,
    const float* __restrict__ bias, float* __restrict__ Cf, u16* __restrict__ Cb,
    int M, int N, int K)
{
  __shared__ __align__(16) u16 As[128 * 64];
  __shared__ __align__(16) u16 Bs[128 * 64];
  const int tid = threadIdx.x, lane = tid & 63, wid = tid >> 6;
  const int wm = wid >> 1, wn = wid & 1;
  const int l15 = lane & 15, l4 = lane >> 4;
  const int m0 = blockIdx.y * 128, n0 = blockIdx.x * 128;
  const int srow = lane >> 3;
  const int schunk = (lane & 7) ^ srow;

  f32x4 acc[4][4];
#pragma unroll
  for (int i = 0; i < 4; ++i)
#pragma unroll
    for (int j = 0; j < 4; ++j) acc[i][j] = {0.f, 0.f, 0.f, 0.f};

  const int nk = K >> 6;
  for (int kt = 0; kt < nk; ++kt) {
    const int kc = kt << 6;
#pragma unroll
    for (int is = 0; is < 4; ++is) {
      int rb = wid * 32 + is * 8;
      int r = rb + srow;
      gload16(A  + (long)(m0 + r) * K + kc + schunk * 8, &As[rb * 64]);
      gload16(Bt + (long)(n0 + r) * K + kc + schunk * 8, &Bs[rb * 64]);
    }
    asm volatile("s_waitcnt vmcnt(0)" ::: "memory");
    __syncthreads();
#pragma unroll
    for (int kk = 0; kk < 2; ++kk) {
      bf16x8 af[4], bfr[4];
#pragma unroll
      for (int mt = 0; mt < 4; ++mt) {
        int row = wm * 64 + mt * 16 + l15;
        af[mt] = *(const bf16x8*)&As[row * 64 + (((kk * 4 + l4) ^ (l15 & 7)) * 8)];
      }
#pragma unroll
      for (int nt = 0; nt < 4; ++nt) {
        int row = wn * 64 + nt * 16 + l15;
        bfr[nt] = *(const bf16x8*)&Bs[row * 64 + (((kk * 4 + l4) ^ (l15 & 7)) * 8)];
      }
#pragma unroll
      for (int mt = 0; mt < 4; ++mt)
#pragma unroll
        for (int nt = 0; nt < 4; ++nt)
          acc[mt][nt] = mfma16(af[mt], bfr[nt], acc[mt][nt]);
    }
    __syncthreads();
  }

#pragma unroll
  for (int mt = 0; mt < 4; ++mt)
#pragma unroll
    for (int nt = 0; nt < 4; ++nt)
#pragma unroll
      for (int r = 0; r < 4; ++r) {
        int row = m0 + wm * 64 + mt * 16 + l4 * 4 + r;
        int col = n0 + wn * 64 + nt * 16 + l15;
        float v = acc[mt][nt][r] + bias[col];
        if (EPI == 0) Cf[(long)row * N + col] = v;
        else          Cb[(long)row * N + col] = f2bf(v);
      }
}

// ---------- flash attention: 8 waves (512 thr), QBLK=128, KBLK=64 ----------
// Static-max softmax (M=12); cvt_pk P-conversion; setprio around MFMA clusters.
__global__ __launch_bounds__(512) void attn_kernel(
    const u16* __restrict__ QKV, const u16* __restrict__ Vtg,
    const int* __restrict__ maskg, u16* __restrict__ Og)
{
  __shared__ __align__(16) u16 Ks[2][64][64];
  __shared__ __align__(16) u16 Vs[2][64][64];
  __shared__ __align__(16) u16 Ps[128][64];
  const int tid = threadIdx.x, lane = tid & 63, w = tid >> 6;   // w in 0..7
  const int l15 = lane & 15, l4 = lane >> 4;
  const int bh = blockIdx.y, qt = blockIdx.x;
  const int b = bh >> 4, h = bh & 15;
  const u16* Qp = QKV + ((long)(b * SDIM + qt * 128)) * 3072 + h * 192;
  const u16* Kp = QKV + (long)(b * SDIM) * 3072 + h * 192 + 64;
  const u16* Vp = Vtg + (long)bh * HD * SDIM;
  const int* mp = maskg + b * SDIM;
  const float SC = 0.18033688011112042f;   // log2(e) / sqrt(64)

  bf16x8 qa[2];
#pragma unroll
  for (int ks = 0; ks < 2; ++ks)
    qa[ks] = *(const bf16x8*)(Qp + (long)(w * 16 + l15) * 3072 + ks * 32 + l4 * 8);

  f32x4 O[4];
  float lsum[4];
#pragma unroll
  for (int dt = 0; dt < 4; ++dt) O[dt] = {0.f, 0.f, 0.f, 0.f};
#pragma unroll
  for (int r = 0; r < 4; ++r) lsum[r] = 0.f;

  char* KsB = (char*)&Ks[0][0][0];
  char* VsB = (char*)&Vs[0][0][0];
  char* PsB = (char*)&Ps[0][0];
  const int srow = lane >> 3;
  const int schunk = (lane & 7) ^ srow;

  auto stage = [&](int kt2, int buf) {
    int row = w * 8 + srow;
    gload16(Kp + (long)(kt2 * 64 + row) * 3072 + schunk * 8,
            (u16*)(KsB + buf * 8192 + (w * 8) * 128));
    gload16(Vp + (long)row * SDIM + kt2 * 64 + schunk * 8,
            (u16*)(VsB + buf * 8192 + (w * 8) * 128));
  };

  stage(0, 0);
  asm volatile("s_waitcnt vmcnt(0)" ::: "memory");
  __syncthreads();

  for (int kt = 0; kt < SDIM / 64; ++kt) {
    const int cur = kt & 1;
    if (kt + 1 < SDIM / 64) stage(kt + 1, cur ^ 1);   // DMA flies under compute

    float mbM[4];
#pragma unroll
    for (int nt = 0; nt < 4; ++nt)
      mbM[nt] = (mp[kt * 64 + nt * 16 + l15] ? 0.f : -1e30f) - 12.0f;  // mask bias - static max

    // S = Q K^T (per wave: 16 x 64)
    f32x4 sc4[4];
    __builtin_amdgcn_s_setprio(1);
#pragma unroll
    for (int nt = 0; nt < 4; ++nt) {
      const char* krow = KsB + cur * 8192 + (nt * 16 + l15) * 128;
      bf16x8 kb0 = *(const bf16x8*)(krow + (((0 + l4) ^ (l15 & 7)) << 4));
      bf16x8 kb1 = *(const bf16x8*)(krow + (((4 + l4) ^ (l15 & 7)) << 4));
      f32x4 z = {0.f, 0.f, 0.f, 0.f};
      z = mfma16(qa[0], kb0, z);
      z = mfma16(qa[1], kb1, z);
      sc4[nt] = z;
    }
    __builtin_amdgcn_s_setprio(0);

    // static-max softmax: P = exp2(s*SC + mb - 12); per-lane partial row-sum
#pragma unroll
    for (int r = 0; r < 4; ++r) {
      float p0 = __builtin_amdgcn_exp2f(sc4[0][r] * SC + mbM[0]);
      float p1 = __builtin_amdgcn_exp2f(sc4[1][r] * SC + mbM[1]);
      float p2 = __builtin_amdgcn_exp2f(sc4[2][r] * SC + mbM[2]);
      float p3 = __builtin_amdgcn_exp2f(sc4[3][r] * SC + mbM[3]);
      lsum[r] += (p0 + p1) + (p2 + p3);
      unsigned u01 = cvt_pk_bf16(p0, p1);   // lo=p0, hi=p1
      unsigned u23 = cvt_pk_bf16(p2, p3);
      int prow = w * 16 + l4 * 4 + r;
      char* rb = PsB + prow * 128;
      int rx = prow & 7, bo = (l15 & 7) * 2, ch = l15 >> 3;
      *(u16*)(rb + (((0 + ch) ^ rx) << 4) + bo) = (u16)u01;
      *(u16*)(rb + (((2 + ch) ^ rx) << 4) + bo) = (u16)(u01 >> 16);
      *(u16*)(rb + (((4 + ch) ^ rx) << 4) + bo) = (u16)u23;
      *(u16*)(rb + (((6 + ch) ^ rx) << 4) + bo) = (u16)(u23 >> 16);
    }
    // P consumed by the same wave only -> lgkmcnt drain, no barrier
    asm volatile("s_waitcnt lgkmcnt(0)" ::: "memory");
    __builtin_amdgcn_sched_barrier(0);

    // O += P V
    __builtin_amdgcn_s_setprio(1);
#pragma unroll
    for (int ks2 = 0; ks2 < 2; ++ks2) {
      bf16x8 pa = *(const bf16x8*)(PsB + (w * 16 + l15) * 128 + (((ks2 * 4 + l4) ^ (l15 & 7)) << 4));
#pragma unroll
      for (int dt = 0; dt < 4; ++dt) {
        const char* vrow = VsB + cur * 8192 + (dt * 16 + l15) * 128;
        bf16x8 vb = *(const bf16x8*)(vrow + (((ks2 * 4 + l4) ^ (l15 & 7)) << 4));
        O[dt] = mfma16(pa, vb, O[dt]);
      }
    }
    __builtin_amdgcn_s_setprio(0);
    __syncthreads();   // drains prefetch vmcnt + syncs buffers (one barrier per tile)
  }

  // one butterfly at the end recovers each row's denominator
  float inv[4];
#pragma unroll
  for (int r = 0; r < 4; ++r) {
    float s = lsum[r];
#pragma unroll
    for (int off = 1; off < 16; off <<= 1) s += __shfl_xor(s, off);
    inv[r] = 1.0f / s;
  }

#pragma unroll
  for (int dt = 0; dt < 4; ++dt)
#pragma unroll
    for (int r = 0; r < 4; ++r) {
      int s = qt * 128 + w * 16 + l4 * 4 + r;
      int d = dt * 16 + l15;
      Og[((long)(b * SDIM + s)) * 1024 + h * HD + d] = f2bf(O[dt][r] * inv[r]);
    }
}

extern "C" void kernel_launch(void* const* d_in, const int* in_sizes, int n_in,
                              void* d_out, int out_size, void* d_ws, size_t ws_size,
                              hipStream_t stream) {
  const float* x    = (const float*)d_in[0];
  const int*   am   = (const int*)d_in[1];
  const float* Wqkv = (const float*)d_in[2];
  const float* bqkv = (const float*)d_in[3];
  const float* Wout = (const float*)d_in[4];
  const float* bout = (const float*)d_in[5];
  float* out = (float*)d_out;
  char* ws = (char*)d_ws;

  u16* xb   = (u16*)(ws);                             // 8 MB   x bf16 [4096][1024]
  u16* AOb  = (u16*)(ws);                             // reused after QKV gemm: attn out bf16
  u16* wqt  = (u16*)(ws + (size_t) 8 * 1024 * 1024);  // 6 MB   W_qkv^T bf16 [3072][1024]
  u16* wot  = (u16*)(ws + (size_t)14 * 1024 * 1024);  // 2 MB   W_out^T bf16 [1024][1024]
  u16* QKVb = (u16*)(ws + (size_t)16 * 1024 * 1024);  // 24 MB  qkv bf16 [4096][3072]
  u16* Vtb  = (u16*)(ws + (size_t)40 * 1024 * 1024);  // 8 MB   V^T bf16 [32][64][2048]

  cvt_kernel<<<2048, 256, 0, stream>>>(x, xb, 524288);
  transpose_cvt<<<dim3(96, 32), 256, 0, stream>>>(Wqkv, wqt, 1024, 3072);
  transpose_cvt<<<dim3(32, 32), 256, 0, stream>>>(Wout, wot, 1024, 1024);
  gemm_bf16<1><<<dim3(24, 32), 256, 0, stream>>>(xb, wqt, bqkv, nullptr, QKVb,
                                                 4096, 3072, 1024);
  vtrans_kernel<<<dim3(32, 32), 256, 0, stream>>>(QKVb, Vtb);
  attn_kernel<<<dim3(16, 32), 512, 0, stream>>>(QKVb, Vtb, am, AOb);
  gemm_bf16<0><<<dim3(8, 32), 256, 0, stream>>>(AOb, wot, bout, out, nullptr,
                                                4096, 1024, 1024);
}